// Round 2
// baseline (358.866 us; speedup 1.0000x reference)
//
#include <hip/hip_runtime.h>
#include <hip/hip_bf16.h>
#include <stdint.h>

typedef __attribute__((ext_vector_type(4))) float  floatx4;
typedef __attribute__((ext_vector_type(8))) short  short8;
typedef __attribute__((ext_vector_type(4))) short  short4_t;

static constexpr int IN   = 512;
static constexpr int OUTF = 1024;
static constexpr int SEQ  = 128;

// output offsets (floats), concatenated in return order
static constexpr long long OFF_SIG  = 0;
static constexpr long long OFF_PHI  = 262144;                   // 2*128*1024
static constexpr long long OFF_BETA = 262144LL + 33554432LL;    // + 2*128*1024*128
static constexpr long long OFF_PI   = OFF_BETA + 262144LL;

__device__ __forceinline__ unsigned short f2bf(float f) {
  union { float f; unsigned u; } x; x.f = f;
  unsigned r = x.u + 0x7fffu + ((x.u >> 16) & 1u);
  return (unsigned short)(r >> 16);
}

// XOR swizzle: row stride 64 shorts (128B). col in shorts.
__device__ __forceinline__ int swz(int row, int col) {
  int g = ((row ^ (row >> 3)) & 7) << 3;
  return row * 64 + (col ^ g);
}

// ---------------------------------------------------------------------------
// out_phi: per (b,s): C[o][t] = sum_i W[o][i] * phi[bs][i][t]
// BM=256, BN=128 (full t), BK=64. 512 threads = 8 waves (4 M x 2 N), 64x64/wave.
// ---------------------------------------------------------------------------
__global__ __launch_bounds__(512) void gemm_phi(
    const float* __restrict__ phi, const float* __restrict__ W,
    float* __restrict__ out) {
  __shared__ short lA[256 * 64];  // W tile   [o][i]  (32 KB)
  __shared__ short lB[128 * 64];  // phi^T    [t][i]  (16 KB)

  // XCD swizzle: 4 consecutive L (one batch's M-tiles) land on one XCD.
  int bid = blockIdx.x;
  int L   = (bid & 7) * 128 + (bid >> 3);   // bijective for 1024 blocks
  int bs  = L >> 2;
  int m0  = (L & 3) * 256;

  const int tid  = threadIdx.x;
  const int lane = tid & 63;
  const int wid  = tid >> 6;
  const int wr   = wid >> 1, wc = wid & 1;

  const float* phiB = phi + (long long)bs * (IN * SEQ);
  float*       outB = out + OFF_PHI + (long long)bs * (OUTF * SEQ);

  floatx4 acc[4][4];
#pragma unroll
  for (int i = 0; i < 4; ++i)
#pragma unroll
    for (int j = 0; j < 4; ++j) acc[i][j] = floatx4{0.f, 0.f, 0.f, 0.f};

  const int tb = (tid & 31) * 4;   // t0 for B staging
  const int ib = (tid >> 5) * 4;   // i-row for B staging

  for (int ks = 0; ks < 8; ++ks) {
    const int i0 = ks * 64;
    __syncthreads();
    // --- stage A: W[m0+row][i0+col], f32 -> bf16 ---
#pragma unroll
    for (int r = 0; r < 4; ++r) {
      int c   = tid + 512 * r;
      int row = c >> 3, col = (c & 7) * 8;
      const float* src = W + (long long)(m0 + row) * IN + i0 + col;
      floatx4 f0 = *(const floatx4*)(src);
      floatx4 f1 = *(const floatx4*)(src + 4);
      short8 v;
      v[0] = (short)f2bf(f0[0]); v[1] = (short)f2bf(f0[1]);
      v[2] = (short)f2bf(f0[2]); v[3] = (short)f2bf(f0[3]);
      v[4] = (short)f2bf(f1[0]); v[5] = (short)f2bf(f1[1]);
      v[6] = (short)f2bf(f1[2]); v[7] = (short)f2bf(f1[3]);
      *(short8*)&lA[swz(row, col)] = v;
    }
    // --- stage B: transpose phi[i][t] -> lB[t][i], f32 -> bf16 ---
    {
      floatx4 q[4];
#pragma unroll
      for (int j = 0; j < 4; ++j)
        q[j] = *(const floatx4*)(phiB + (long long)(i0 + ib + j) * SEQ + tb);
#pragma unroll
      for (int jj = 0; jj < 4; ++jj) {
        short4_t v;
        v[0] = (short)f2bf(q[0][jj]); v[1] = (short)f2bf(q[1][jj]);
        v[2] = (short)f2bf(q[2][jj]); v[3] = (short)f2bf(q[3][jj]);
        *(short4_t*)&lB[swz(tb + jj, ib)] = v;
      }
    }
    __syncthreads();
    // --- MFMA ---
#pragma unroll
    for (int kk = 0; kk < 2; ++kk) {
      const int colb = kk * 32 + (lane >> 4) * 8;
      short8 af[4], bf[4];
#pragma unroll
      for (int mi = 0; mi < 4; ++mi) {
        int row = wr * 64 + mi * 16 + (lane & 15);
        af[mi] = *(const short8*)&lA[swz(row, colb)];
      }
#pragma unroll
      for (int ni = 0; ni < 4; ++ni) {
        int row = wc * 64 + ni * 16 + (lane & 15);
        bf[ni] = *(const short8*)&lB[swz(row, colb)];
      }
#pragma unroll
      for (int mi = 0; mi < 4; ++mi)
#pragma unroll
        for (int ni = 0; ni < 4; ++ni)
          acc[mi][ni] = __builtin_amdgcn_mfma_f32_16x16x32_bf16(
              af[mi], bf[ni], acc[mi][ni], 0, 0, 0);
    }
  }
  // --- epilogue: C[m][n] -> out_phi[bs][o][t]; col=lane&15, row=(lane>>4)*4+r
#pragma unroll
  for (int mi = 0; mi < 4; ++mi)
#pragma unroll
    for (int ni = 0; ni < 4; ++ni) {
      int col = wc * 64 + ni * 16 + (lane & 15);
#pragma unroll
      for (int r = 0; r < 4; ++r) {
        int row = m0 + wr * 64 + mi * 16 + (lane >> 4) * 4 + r;
        outB[(long long)row * SEQ + col] = acc[mi][ni][r];
      }
    }
}

// ---------------------------------------------------------------------------
// Fused: out_signal, out_beta (exact f32 dot) + top-4 |sig_i * W_oi| indices.
// One thread per (bs, o); block = 256 threads; grid = 256 bs * 4 o-chunks.
// ---------------------------------------------------------------------------
__global__ __launch_bounds__(256) void fused_sbp(
    const float* __restrict__ sig, const float* __restrict__ beta,
    const float* __restrict__ W, float* __restrict__ out) {
  __shared__ float ls[512], lb[512], la[512];
  const int bid = blockIdx.x;
  const int bs  = bid >> 2;
  const int oc  = bid & 3;
  const int tid = threadIdx.x;

#pragma unroll
  for (int r = 0; r < 2; ++r) {
    int i = tid + 256 * r;
    float s = sig[(long long)bs * 512 + i];
    ls[i] = s;
    la[i] = fabsf(s);
    lb[i] = beta[(long long)bs * 512 + i];
  }
  __syncthreads();

  const int o = oc * 256 + tid;
  const float* wrow = W + (long long)o * 512;
  float dsum = 0.f, bsum = 0.f;
  float tv0 = -1.f, tv1 = -1.f, tv2 = -1.f, tv3 = -1.f;
  int   ti0 = 0, ti1 = 0, ti2 = 0, ti3 = 0;

  for (int i = 0; i < 512; i += 4) {
    floatx4 w = *(const floatx4*)(wrow + i);
    floatx4 s = *(const floatx4*)(ls + i);
    floatx4 b = *(const floatx4*)(lb + i);
    floatx4 a = *(const floatx4*)(la + i);
#pragma unroll
    for (int j = 0; j < 4; ++j) {
      dsum = fmaf(s[j], w[j], dsum);
      bsum = fmaf(b[j], w[j], bsum);
      float v = fabsf(w[j]) * a[j];   // == |sig_i * W_oi| bit-exactly
      if (v > tv3) {                  // strict >: stable ties like lax.top_k
        int idx = i + j;
        if (v > tv0) {
          tv3 = tv2; ti3 = ti2; tv2 = tv1; ti2 = ti1; tv1 = tv0; ti1 = ti0;
          tv0 = v; ti0 = idx;
        } else if (v > tv1) {
          tv3 = tv2; ti3 = ti2; tv2 = tv1; ti2 = ti1; tv1 = v; ti1 = idx;
        } else if (v > tv2) {
          tv3 = tv2; ti3 = ti2; tv2 = v; ti2 = idx;
        } else {
          tv3 = v; ti3 = idx;
        }
      }
    }
  }

  const long long base = (long long)bs * 1024 + o;
  out[OFF_SIG + base]  = dsum;
  out[OFF_BETA + base] = bsum;
  floatx4 pv;
  pv[0] = (float)ti0; pv[1] = (float)ti1; pv[2] = (float)ti2; pv[3] = (float)ti3;
  *(floatx4*)(out + OFF_PI + base * 4) = pv;
}

extern "C" void kernel_launch(void* const* d_in, const int* in_sizes, int n_in,
                              void* d_out, int out_size, void* d_ws, size_t ws_size,
                              hipStream_t stream) {
  const float* sig  = (const float*)d_in[0];
  const float* phi  = (const float*)d_in[1];
  const float* beta = (const float*)d_in[2];
  const float* W    = (const float*)d_in[3];
  float* out = (float*)d_out;
  (void)in_sizes; (void)n_in; (void)out_size; (void)d_ws; (void)ws_size;

  hipLaunchKernelGGL(gemm_phi, dim3(1024), dim3(512), 0, stream, phi, W, out);
  hipLaunchKernelGGL(fused_sbp, dim3(1024), dim3(256), 0, stream, sig, beta, W, out);
}

// Round 5
// 319.734 us; speedup vs baseline: 1.1224x; 1.1224x over previous
//
#include <hip/hip_runtime.h>
#include <hip/hip_bf16.h>
#include <stdint.h>

typedef __attribute__((ext_vector_type(4))) float  floatx4;
typedef __attribute__((ext_vector_type(8))) short  short8;
typedef __attribute__((ext_vector_type(4))) short  short4_t;

static constexpr int IN   = 512;
static constexpr int OUTF = 1024;
static constexpr int SEQ  = 128;

// output offsets (floats), concatenated in return order
static constexpr long long OFF_SIG  = 0;
static constexpr long long OFF_PHI  = 262144;                   // 2*128*1024
static constexpr long long OFF_BETA = 262144LL + 33554432LL;    // + 2*128*1024*128
static constexpr long long OFF_PI   = OFF_BETA + 262144LL;

// workspace layout (ushort elems): Wb[1024][512] then phiT[256][128][512]
static constexpr long long WS_WB_ELEMS   = 1024LL * 512;
static constexpr long long WS_PHIT_ELEMS = 256LL * 128 * 512;
static constexpr size_t    WS_NEED = (size_t)(WS_WB_ELEMS + WS_PHIT_ELEMS) * 2;

__device__ __forceinline__ unsigned short f2bf(float f) {
  union { float f; unsigned u; } x; x.f = f;
  unsigned r = x.u + 0x7fffu + ((x.u >> 16) & 1u);
  return (unsigned short)(r >> 16);
}

typedef const __attribute__((address_space(1))) void* gptr_t;
typedef __attribute__((address_space(3))) void* lptr_t;
__device__ __forceinline__ void gl_lds16(const void* g, void* l) {
  __builtin_amdgcn_global_load_lds((gptr_t)g, (lptr_t)l, 16, 0, 0);
}

// ---------------------------------------------------------------------------
// prep_w: W f32 [1024][512] -> Wb bf16 (row-major unchanged)
// ---------------------------------------------------------------------------
__global__ __launch_bounds__(256) void prep_w(const float* __restrict__ W,
                                              unsigned short* __restrict__ Wb) {
  long long base = ((long long)blockIdx.x * 256 + threadIdx.x) * 8;
  floatx4 f0 = *(const floatx4*)(W + base);
  floatx4 f1 = *(const floatx4*)(W + base + 4);
  short8 v;
  v[0] = (short)f2bf(f0[0]); v[1] = (short)f2bf(f0[1]);
  v[2] = (short)f2bf(f0[2]); v[3] = (short)f2bf(f0[3]);
  v[4] = (short)f2bf(f1[0]); v[5] = (short)f2bf(f1[1]);
  v[6] = (short)f2bf(f1[2]); v[7] = (short)f2bf(f1[3]);
  *(short8*)(Wb + base) = v;
}

// ---------------------------------------------------------------------------
// prep_phiT: phi[bs][i][t] f32 -> phiT[bs][t][i] bf16.
// Block: one bs x 64-row i-chunk. LDS 64x128 f32, rotate-swizzled
// (col' = (t + 4*(i>>2)) & 127) so column reads are conflict-free.
// ---------------------------------------------------------------------------
__global__ __launch_bounds__(256) void prep_phiT(const float* __restrict__ phi,
                                                 unsigned short* __restrict__ phiT) {
  __shared__ float lt[64 * 128];  // 32 KB
  const int bs = blockIdx.x >> 3;
  const int i0 = (blockIdx.x & 7) * 64;
  const int tid = threadIdx.x;
  const float* src = phi + (long long)bs * (IN * SEQ) + (long long)i0 * SEQ;

#pragma unroll
  for (int r = 0; r < 8; ++r) {
    int idx = tid + 256 * r;            // floatx4 index, 2048 total
    int row = idx >> 5;                 // i within chunk
    int colw = (idx & 31) * 4;          // t
    int colp = (colw + 4 * (row >> 2)) & 127;
    *(floatx4*)&lt[row * 128 + colp] = *(const floatx4*)(src + (long long)row * SEQ + colw);
  }
  __syncthreads();

  const int ioff = (tid & 15) * 4;      // i>>2 == tid&15 for all 4 elems
#pragma unroll
  for (int p = 0; p < 8; ++p) {
    int t = p * 16 + (tid >> 4);
    int col = (t + 4 * (tid & 15)) & 127;
    short4_t v;
#pragma unroll
    for (int k = 0; k < 4; ++k) v[k] = (short)f2bf(lt[(ioff + k) * 128 + col]);
    *(short4_t*)(phiT + ((long long)(bs * SEQ + t)) * IN + i0 + ioff) = v;
  }
}

// ---------------------------------------------------------------------------
// gemm_phi2: C[o][t] = sum_i Wb[o][i] * phiT[bs][t][i], out f32.
// BM=128, BN=128, BK=64. 256 thr = 4 waves (2x2), 64x64/wave.
// Double-buffered LDS (64KB), global_load_lds w/ pre-swizzled source,
// counted vmcnt(8), raw s_barrier (no vmcnt(0) drain mid-loop).
// ---------------------------------------------------------------------------
__global__ __launch_bounds__(256, 2) void gemm_phi2(
    const unsigned short* __restrict__ Wb,
    const unsigned short* __restrict__ phiT,
    float* __restrict__ out) {
  __shared__ unsigned short sA[2][128 * 64];  // 16 KB each
  __shared__ unsigned short sB[2][128 * 64];

  // XCD swizzle: the 8 M-tiles of one bs stay on one XCD (share B panel).
  const int bid = blockIdx.x;
  const int L   = (bid & 7) * 256 + (bid >> 3);   // bijective for 2048
  const int bs  = L >> 3;
  const int m0  = (L & 7) * 128;

  const int tid  = threadIdx.x;
  const int lane = tid & 63;
  const int wid  = tid >> 6;
  const int wr   = wid >> 1, wc = wid & 1;

  const unsigned short* phiB = phiT + (long long)bs * (SEQ * IN);
  float* outB = out + OFF_PHI + (long long)bs * (OUTF * SEQ);

  // staging geometry: instr r covers rows [r*32+wid*8, +8), 128B/row
  const int srow  = wid * 8 + (lane >> 3);   // + r*32
  const int schnk = lane & 7;

  floatx4 acc[4][4];
#pragma unroll
  for (int i = 0; i < 4; ++i)
#pragma unroll
    for (int j = 0; j < 4; ++j) acc[i][j] = floatx4{0.f, 0.f, 0.f, 0.f};

#define STAGE(buf, kstep)                                                      \
  {                                                                            \
    const int i0 = (kstep) * 64;                                               \
    _Pragma("unroll")                                                          \
    for (int r = 0; r < 4; ++r) {                                              \
      int row = r * 32 + srow;                                                 \
      gl_lds16(Wb + (long long)(m0 + row) * IN + i0 + ((schnk ^ (row & 7)) << 3), \
               &sA[buf][(r * 32 + wid * 8) * 64]);                             \
      gl_lds16(phiB + (long long)row * IN + i0 + ((schnk ^ (row & 7)) << 3),   \
               &sB[buf][(r * 32 + wid * 8) * 64]);                             \
    }                                                                          \
  }

  STAGE(0, 0);

  const int ra  = wr * 64 + (lane & 15);
  const int rb  = wc * 64 + (lane & 15);
  const int sa7 = ra & 7, sb7 = rb & 7;

#pragma unroll
  for (int k = 0; k < 8; ++k) {
    const int cur = k & 1;
    if (k < 7) {
      STAGE(cur ^ 1, k + 1);
      asm volatile("s_waitcnt vmcnt(8)" ::: "memory");  // wait buf[cur] only
    } else {
      asm volatile("s_waitcnt vmcnt(0)" ::: "memory");
    }
    __builtin_amdgcn_s_barrier();
    __builtin_amdgcn_sched_barrier(0);

#pragma unroll
    for (int kk = 0; kk < 2; ++kk) {
      const int j  = kk * 4 + (lane >> 4);
      const int ja = (j ^ sa7) << 3;
      const int jb = (j ^ sb7) << 3;
      short8 af[4], bv[4];
#pragma unroll
      for (int mi = 0; mi < 4; ++mi)
        af[mi] = *(const short8*)&sA[cur][(ra + mi * 16) * 64 + ja];
#pragma unroll
      for (int ni = 0; ni < 4; ++ni)
        bv[ni] = *(const short8*)&sB[cur][(rb + ni * 16) * 64 + jb];
#pragma unroll
      for (int mi = 0; mi < 4; ++mi)
#pragma unroll
        for (int ni = 0; ni < 4; ++ni)
          acc[mi][ni] = __builtin_amdgcn_mfma_f32_16x16x32_bf16(
              af[mi], bv[ni], acc[mi][ni], 0, 0, 0);
    }
    __builtin_amdgcn_s_barrier();   // reads done before next STAGE overwrites
  }
#undef STAGE

#pragma unroll
  for (int mi = 0; mi < 4; ++mi)
#pragma unroll
    for (int ni = 0; ni < 4; ++ni) {
      int t = wc * 64 + ni * 16 + (lane & 15);
#pragma unroll
      for (int rg = 0; rg < 4; ++rg) {
        int o = m0 + wr * 64 + mi * 16 + (lane >> 4) * 4 + rg;
        outB[(long long)o * SEQ + t] = acc[mi][ni][rg];
      }
    }
}

// ---------------------------------------------------------------------------
// LEGACY gemm (verified round-2): used only if ws_size < WS_NEED.
// ---------------------------------------------------------------------------
__device__ __forceinline__ int swz(int row, int col) {
  int g = ((row ^ (row >> 3)) & 7) << 3;
  return row * 64 + (col ^ g);
}

__global__ __launch_bounds__(512) void gemm_phi(
    const float* __restrict__ phi, const float* __restrict__ W,
    float* __restrict__ out) {
  __shared__ short lA[256 * 64];
  __shared__ short lB[128 * 64];
  int bid = blockIdx.x;
  int L   = (bid & 7) * 128 + (bid >> 3);
  int bs  = L >> 2;
  int m0  = (L & 3) * 256;
  const int tid  = threadIdx.x;
  const int lane = tid & 63;
  const int wid  = tid >> 6;
  const int wr   = wid >> 1, wc = wid & 1;
  const float* phiB = phi + (long long)bs * (IN * SEQ);
  float*       outB = out + OFF_PHI + (long long)bs * (OUTF * SEQ);
  floatx4 acc[4][4];
#pragma unroll
  for (int i = 0; i < 4; ++i)
#pragma unroll
    for (int j = 0; j < 4; ++j) acc[i][j] = floatx4{0.f, 0.f, 0.f, 0.f};
  const int tb = (tid & 31) * 4;
  const int ib = (tid >> 5) * 4;
  for (int ks = 0; ks < 8; ++ks) {
    const int i0 = ks * 64;
    __syncthreads();
#pragma unroll
    for (int r = 0; r < 4; ++r) {
      int c   = tid + 512 * r;
      int row = c >> 3, col = (c & 7) * 8;
      const float* src = W + (long long)(m0 + row) * IN + i0 + col;
      floatx4 f0 = *(const floatx4*)(src);
      floatx4 f1 = *(const floatx4*)(src + 4);
      short8 v;
      v[0] = (short)f2bf(f0[0]); v[1] = (short)f2bf(f0[1]);
      v[2] = (short)f2bf(f0[2]); v[3] = (short)f2bf(f0[3]);
      v[4] = (short)f2bf(f1[0]); v[5] = (short)f2bf(f1[1]);
      v[6] = (short)f2bf(f1[2]); v[7] = (short)f2bf(f1[3]);
      *(short8*)&lA[swz(row, col)] = v;
    }
    {
      floatx4 q[4];
#pragma unroll
      for (int j = 0; j < 4; ++j)
        q[j] = *(const floatx4*)(phiB + (long long)(i0 + ib + j) * SEQ + tb);
#pragma unroll
      for (int jj = 0; jj < 4; ++jj) {
        short4_t v;
        v[0] = (short)f2bf(q[0][jj]); v[1] = (short)f2bf(q[1][jj]);
        v[2] = (short)f2bf(q[2][jj]); v[3] = (short)f2bf(q[3][jj]);
        *(short4_t*)&lB[swz(tb + jj, ib)] = v;
      }
    }
    __syncthreads();
#pragma unroll
    for (int kk = 0; kk < 2; ++kk) {
      const int colb = kk * 32 + (lane >> 4) * 8;
      short8 af[4], bf[4];
#pragma unroll
      for (int mi = 0; mi < 4; ++mi) {
        int row = wr * 64 + mi * 16 + (lane & 15);
        af[mi] = *(const short8*)&lA[swz(row, colb)];
      }
#pragma unroll
      for (int ni = 0; ni < 4; ++ni) {
        int row = wc * 64 + ni * 16 + (lane & 15);
        bf[ni] = *(const short8*)&lB[swz(row, colb)];
      }
#pragma unroll
      for (int mi = 0; mi < 4; ++mi)
#pragma unroll
        for (int ni = 0; ni < 4; ++ni)
          acc[mi][ni] = __builtin_amdgcn_mfma_f32_16x16x32_bf16(
              af[mi], bf[ni], acc[mi][ni], 0, 0, 0);
    }
  }
#pragma unroll
  for (int mi = 0; mi < 4; ++mi)
#pragma unroll
    for (int ni = 0; ni < 4; ++ni) {
      int col = wc * 64 + ni * 16 + (lane & 15);
#pragma unroll
      for (int r = 0; r < 4; ++r) {
        int row = m0 + wr * 64 + mi * 16 + (lane >> 4) * 4 + r;
        outB[(long long)row * SEQ + col] = acc[mi][ni][r];
      }
    }
}

// ---------------------------------------------------------------------------
// Fused: out_signal, out_beta (exact f32 dot) + top-4 |sig_i * W_oi| indices.
// ---------------------------------------------------------------------------
__global__ __launch_bounds__(256) void fused_sbp(
    const float* __restrict__ sig, const float* __restrict__ beta,
    const float* __restrict__ W, float* __restrict__ out) {
  __shared__ float ls[512], lb[512], la[512];
  const int bid = blockIdx.x;
  const int bs  = bid >> 2;
  const int oc  = bid & 3;
  const int tid = threadIdx.x;

#pragma unroll
  for (int r = 0; r < 2; ++r) {
    int i = tid + 256 * r;
    float s = sig[(long long)bs * 512 + i];
    ls[i] = s;
    la[i] = fabsf(s);
    lb[i] = beta[(long long)bs * 512 + i];
  }
  __syncthreads();

  const int o = oc * 256 + tid;
  const float* wrow = W + (long long)o * 512;
  float dsum = 0.f, bsum = 0.f;
  float tv0 = -1.f, tv1 = -1.f, tv2 = -1.f, tv3 = -1.f;
  int   ti0 = 0, ti1 = 0, ti2 = 0, ti3 = 0;

  for (int i = 0; i < 512; i += 4) {
    floatx4 w = *(const floatx4*)(wrow + i);
    floatx4 s = *(const floatx4*)(ls + i);
    floatx4 b = *(const floatx4*)(lb + i);
    floatx4 a = *(const floatx4*)(la + i);
#pragma unroll
    for (int j = 0; j < 4; ++j) {
      dsum = fmaf(s[j], w[j], dsum);
      bsum = fmaf(b[j], w[j], bsum);
      float v = fabsf(w[j]) * a[j];   // == |sig_i * W_oi| bit-exactly
      if (v > tv3) {                  // strict >: stable ties like lax.top_k
        int idx = i + j;
        if (v > tv0) {
          tv3 = tv2; ti3 = ti2; tv2 = tv1; ti2 = ti1; tv1 = tv0; ti1 = ti0;
          tv0 = v; ti0 = idx;
        } else if (v > tv1) {
          tv3 = tv2; ti3 = ti2; tv2 = tv1; ti2 = ti1; tv1 = v; ti1 = idx;
        } else if (v > tv2) {
          tv3 = tv2; ti3 = ti2; tv2 = v; ti2 = idx;
        } else {
          tv3 = v; ti3 = idx;
        }
      }
    }
  }

  const long long base = (long long)bs * 1024 + o;
  out[OFF_SIG + base]  = dsum;
  out[OFF_BETA + base] = bsum;
  floatx4 pv;
  pv[0] = (float)ti0; pv[1] = (float)ti1; pv[2] = (float)ti2; pv[3] = (float)ti3;
  *(floatx4*)(out + OFF_PI + base * 4) = pv;
}

extern "C" void kernel_launch(void* const* d_in, const int* in_sizes, int n_in,
                              void* d_out, int out_size, void* d_ws, size_t ws_size,
                              hipStream_t stream) {
  const float* sig  = (const float*)d_in[0];
  const float* phi  = (const float*)d_in[1];
  const float* beta = (const float*)d_in[2];
  const float* W    = (const float*)d_in[3];
  float* out = (float*)d_out;
  (void)in_sizes; (void)n_in; (void)out_size;

  if (ws_size >= WS_NEED) {
    unsigned short* Wb   = (unsigned short*)d_ws;
    unsigned short* phiT = Wb + WS_WB_ELEMS;
    hipLaunchKernelGGL(prep_w, dim3(256), dim3(256), 0, stream, W, Wb);
    hipLaunchKernelGGL(prep_phiT, dim3(2048), dim3(256), 0, stream, phi, phiT);
    hipLaunchKernelGGL(gemm_phi2, dim3(2048), dim3(256), 0, stream, Wb, phiT, out);
  } else {
    hipLaunchKernelGGL(gemm_phi, dim3(1024), dim3(512), 0, stream, phi, W, out);
  }
  hipLaunchKernelGGL(fused_sbp, dim3(1024), dim3(256), 0, stream, sig, beta, W, out);
}